// Round 1
// baseline (1081.545 us; speedup 1.0000x reference)
//
#include <hip/hip_runtime.h>
#include <stdint.h>

// Problem constants (fixed by the reference).
#define Bn 2
#define Hn 16
#define Sn 2048
#define Dn 64
#define TQ 64                 // q rows per workgroup
#define KSPLIT 8              // k-range split across workgroups
#define KRANGE (Sn / KSPLIT)  // 256
#define KITER 16              // k columns per iteration
#define NITER (KRANGE / KITER)

typedef __attribute__((ext_vector_type(8))) short short8;
typedef __attribute__((ext_vector_type(4))) short short4v;
typedef __attribute__((ext_vector_type(4))) float float4v;

__device__ __forceinline__ short f2bf(float f) {
    uint32_t u = __builtin_bit_cast(uint32_t, f);
    u += 0x7fffu + ((u >> 16) & 1u);   // round-to-nearest-even
    return (short)(u >> 16);
}
__device__ __forceinline__ float bf2f(short s) {
    uint32_t u = ((uint32_t)(uint16_t)s) << 16;
    return __builtin_bit_cast(float, u);
}
// Load 8 consecutive fp32, convert to a bf16x8 MFMA fragment.
__device__ __forceinline__ short8 load_bf8(const float* p) {
    float4v a = *(const float4v*)p;
    float4v b = *(const float4v*)(p + 4);
    short8 r;
    r[0] = f2bf(a[0]); r[1] = f2bf(a[1]); r[2] = f2bf(a[2]); r[3] = f2bf(a[3]);
    r[4] = f2bf(b[0]); r[5] = f2bf(b[1]); r[6] = f2bf(b[2]); r[7] = f2bf(b[3]);
    return r;
}

#define MFMA(a, b, c) __builtin_amdgcn_mfma_f32_16x16x32_bf16((a), (b), (c), 0, 0, 0)

// Grid: 512 blocks of 512 threads. Block = 8 waves, wave w owns heads {2w,2w+1}.
// Block covers (b, q-tile of 64, k-range of 256). Softmax over the 16 heads is
// done per (q,k) position: in-lane sum of the wave's 2 heads, then an 8-wave
// LDS reduction (bf16 partials; 0.4% rel err << 2% tolerance).
__global__ __launch_bounds__(512, 2) void attn_fused(
    const float* __restrict__ Q, const float* __restrict__ K,
    const float* __restrict__ V, float* __restrict__ Out,
    float* __restrict__ Attn)
{
    // LDS: 8*16*68*2 + 16*68*4 + 16*64*20*2 = 17408 + 4352 + 40960 = 62720 B
    __shared__ short part[8][16][68];   // per-wave partial head-sums, [w][k][q+pad]
    __shared__ float den[16][68];       // softmax denominators, [k][q+pad]
    __shared__ short pbuf[16][64][20];  // attn bf16, [h][q][k+pad] (A-layout source)

    const int bid  = blockIdx.x;
    const int qb   = bid & 31;        // consecutive blocks share (b,ks) -> K/V L2 reuse
    const int t2   = bid >> 5;
    const int ks   = t2 & 7;
    const int b    = t2 >> 3;

    const int tid  = threadIdx.x;
    const int wave = tid >> 6;
    const int lane = tid & 63;
    const int quad = lane >> 4;
    const int l16  = lane & 15;

    const int h0 = wave * 2;
    const int q0 = qb * TQ;
    const int k0 = ks * KRANGE;

    // Resident Q fragments: A[m=l16][k=quad*8+j], per (head, qsub, d-chunk).
    short8 aq[2][4][2];
#pragma unroll
    for (int hi = 0; hi < 2; ++hi) {
        const float* qbase = Q + (size_t)(b * Hn + h0 + hi) * Sn * Dn;
#pragma unroll
        for (int qs = 0; qs < 4; ++qs) {
            const float* rp = qbase + (size_t)(q0 + qs * 16 + l16) * Dn + quad * 8;
            aq[hi][qs][0] = load_bf8(rp);
            aq[hi][qs][1] = load_bf8(rp + 32);
        }
    }

    // Out accumulators: [head][qsub][d-chunk] 16x16 C-frags.
    float4v acc[2][4][4];
#pragma unroll
    for (int hi = 0; hi < 2; ++hi)
#pragma unroll
        for (int qs = 0; qs < 4; ++qs)
#pragma unroll
            for (int dc = 0; dc < 4; ++dc)
                acc[hi][qs][dc] = (float4v){0.f, 0.f, 0.f, 0.f};

    for (int it = 0; it < NITER; ++it) {
        const int kb = k0 + it * KITER;

        // --- K fragments: B[k=quad*8+j][n=l16] = K[kb+l16][d] ---
        short8 bk[2][2];
#pragma unroll
        for (int hi = 0; hi < 2; ++hi) {
            const float* kp = K + (size_t)(b * Hn + h0 + hi) * Sn * Dn
                                + (size_t)(kb + l16) * Dn + quad * 8;
            bk[hi][0] = load_bf8(kp);
            bk[hi][1] = load_bf8(kp + 32);
        }

        // --- scores -> e = exp(score/8), C-layout (q=quad*4+r, k=l16) ---
        float4v e[2][4];
#pragma unroll
        for (int hi = 0; hi < 2; ++hi)
#pragma unroll
            for (int qs = 0; qs < 4; ++qs) {
                float4v c = (float4v){0.f, 0.f, 0.f, 0.f};
                c = MFMA(aq[hi][qs][0], bk[hi][0], c);
                c = MFMA(aq[hi][qs][1], bk[hi][1], c);
                float4v ee;
#pragma unroll
                for (int r = 0; r < 4; ++r) ee[r] = __expf(c[r] * 0.125f);
                e[hi][qs] = ee;
            }

        // --- per-wave head partial sums -> LDS (bf16, packed b64) ---
#pragma unroll
        for (int qs = 0; qs < 4; ++qs) {
            float4v p = e[0][qs] + e[1][qs];
            short4v pb;
#pragma unroll
            for (int r = 0; r < 4; ++r) pb[r] = f2bf(p[r]);
            *(short4v*)&part[wave][l16][qs * 16 + quad * 4] = pb;
        }
        __syncthreads();

        // --- reduce over the 8 waves: 1024 positions / 512 threads ---
#pragma unroll
        for (int i = 0; i < 2; ++i) {
            int pos = tid + i * 512;
            int kk = pos >> 6, qq = pos & 63;
            float s = 0.f;
#pragma unroll
            for (int w = 0; w < 8; ++w) s += bf2f(part[w][kk][qq]);
            den[kk][qq] = s;
        }
        __syncthreads();

        // --- attn = e / den; NT-store to global; bf16 copy into pbuf ---
#pragma unroll
        for (int qs = 0; qs < 4; ++qs) {
            float4v d4 = *(const float4v*)&den[l16][qs * 16 + quad * 4];
            float4v r4;
#pragma unroll
            for (int r = 0; r < 4; ++r) r4[r] = __builtin_amdgcn_rcpf(d4[r]);
#pragma unroll
            for (int hi = 0; hi < 2; ++hi) {
                float4v a = e[hi][qs] * r4;
                const int h = h0 + hi;
                size_t base = ((size_t)(b * Hn + h) * Sn + (size_t)(q0 + qs * 16 + quad * 4)) * Sn
                              + kb + l16;
#pragma unroll
                for (int r = 0; r < 4; ++r)
                    __builtin_nontemporal_store(a[r], Attn + base + (size_t)r * Sn);
#pragma unroll
                for (int r = 0; r < 4; ++r)
                    pbuf[h][qs * 16 + quad * 4 + r][l16] = f2bf(a[r]);
            }
        }
        __syncthreads();   // publish pbuf (also orders within-wave ds write->read)

        // --- PV: out += P @ V, K=16 emulated on the K=32 MFMA (slots j=0..3 real) ---
#pragma unroll
        for (int hi = 0; hi < 2; ++hi) {
            const int h = h0 + hi;
            short8 bv[4];
#pragma unroll
            for (int dc = 0; dc < 4; ++dc) {
                const float* vp = V + (size_t)(b * Hn + h) * Sn * Dn
                                    + (size_t)(kb + quad * 4) * Dn + dc * 16 + l16;
                short8 t;
#pragma unroll
                for (int j = 0; j < 4; ++j) t[j] = f2bf(vp[(size_t)j * Dn]);
                t[4] = 0; t[5] = 0; t[6] = 0; t[7] = 0;
                bv[dc] = t;
            }
#pragma unroll
            for (int qs = 0; qs < 4; ++qs) {
                short4v p4 = *(const short4v*)&pbuf[h][qs * 16 + l16][quad * 4];
                short8 av = (short8){p4[0], p4[1], p4[2], p4[3], 0, 0, 0, 0};
#pragma unroll
                for (int dc = 0; dc < 4; ++dc)
                    acc[hi][qs][dc] = MFMA(av, bv[dc], acc[hi][qs][dc]);
            }
        }
    }

    // --- epilogue: atomic-accumulate the k-split partials into Out ---
#pragma unroll
    for (int hi = 0; hi < 2; ++hi)
#pragma unroll
        for (int qs = 0; qs < 4; ++qs)
#pragma unroll
            for (int dc = 0; dc < 4; ++dc) {
                float* op = Out + ((size_t)(b * Hn + h0 + hi) * Sn
                                   + (size_t)(q0 + qs * 16 + quad * 4)) * Dn + dc * 16 + l16;
#pragma unroll
                for (int r = 0; r < 4; ++r)
                    unsafeAtomicAdd(op + (size_t)r * Dn, acc[hi][qs][dc][r]);
            }
}

extern "C" void kernel_launch(void* const* d_in, const int* in_sizes, int n_in,
                              void* d_out, int out_size, void* d_ws, size_t ws_size,
                              hipStream_t stream) {
    const float* q = (const float*)d_in[0];
    const float* k = (const float*)d_in[1];
    const float* v = (const float*)d_in[2];
    float* out  = (float*)d_out;
    float* attn = out + (size_t)Bn * Hn * Sn * Dn;   // outputs concatenated: (out, attn)

    // Out is accumulated via atomics across KSPLIT partials -> zero it first.
    hipMemsetAsync(d_out, 0, (size_t)Bn * Hn * Sn * Dn * sizeof(float), stream);

    attn_fused<<<dim3(Bn * (Sn / TQ) * KSPLIT), dim3(512), 0, stream>>>(q, k, v, out, attn);
}